// Round 1
// baseline (1366.349 us; speedup 1.0000x reference)
//
#include <hip/hip_runtime.h>
#include <cstdint>
#include <cstddef>

#define NTOK   8192
#define DIMM   2048
#define KVD    512
#define NHEAD  16
#define NKVH   4
#define HDIM   128
#define NDEPTH 8
#define EPSI   1.1920929e-07f
#define QSCALE 0.08838834764831845f      /* 1/sqrt(128) */
#define NLN64  (-0.14391156831212787f)   /* -ln(10000)/64 */
#define LDA    40                        /* padded LDS stride (bf16 elems) */

typedef __attribute__((ext_vector_type(8))) short bf16x8;
typedef __attribute__((ext_vector_type(4))) float f32x4;

__device__ __forceinline__ unsigned short f2bf(float f) {
  union { float f; unsigned int u; } v; v.f = f;
  unsigned int u = v.u;
  return (unsigned short)((u + 0x7fffu + ((u >> 16) & 1u)) >> 16);
}
__device__ __forceinline__ float bf2f(unsigned short h) {
  union { unsigned int u; float f; } v; v.u = ((unsigned int)h) << 16;
  return v.f;
}
__device__ __forceinline__ f32x4 mfma16(bf16x8 a, bf16x8 b, f32x4 c) {
  return __builtin_amdgcn_mfma_f32_16x16x32_bf16(a, b, c, 0, 0, 0);
}

// ---------------- weight fp32 -> bf16 ----------------
__global__ __launch_bounds__(256) void cvt_kernel(const float* __restrict__ in,
                                                  unsigned short* __restrict__ out, int n4) {
  int i = blockIdx.x * 256 + threadIdx.x;
  if (i < n4) {
    float4 f = *(const float4*)(in + (size_t)i * 4);
    *(ushort4*)(out + (size_t)i * 4) = make_ushort4(f2bf(f.x), f2bf(f.y), f2bf(f.z), f2bf(f.w));
  }
}

// ---------------- Q GEMM: q = rmsnorm(x@Wq^T) -> rope -> *gain*scale -> bf16 ----------------
__global__ __launch_bounds__(256, 2)
void gemm_q_kernel(const float* __restrict__ X, const unsigned short* __restrict__ W,
                   const float* __restrict__ QG, unsigned short* __restrict__ Q) {
  __shared__ unsigned short lA[128 * LDA];
  __shared__ unsigned short lB[128 * LDA];
  const int t = threadIdx.x;
  const int lane = t & 63, w = t >> 6;
  const int m = lane & 15, q4 = lane >> 4;
  const int row0 = blockIdx.y * 128;
  const int h = blockIdx.x;
  const int col0 = h * 128;

  f32x4 acc[2][8];
#pragma unroll
  for (int i = 0; i < 2; ++i)
#pragma unroll
    for (int j = 0; j < 8; ++j) acc[i][j] = (f32x4){0.f, 0.f, 0.f, 0.f};

  const float* aptr[4]; const unsigned short* bptr[4]; int dst[4];
#pragma unroll
  for (int it = 0; it < 4; ++it) {
    int idx = t + it * 256;
    int r = idx >> 3, c = (idx & 7) * 4;
    aptr[it] = X + (size_t)(row0 + r) * DIMM + c;
    bptr[it] = W + (size_t)(col0 + r) * DIMM + c;
    dst[it] = r * LDA + c;
  }
  for (int kt = 0; kt < DIMM; kt += 32) {
#pragma unroll
    for (int it = 0; it < 4; ++it) {
      float4 f = *(const float4*)(aptr[it] + kt);
      *(ushort4*)&lA[dst[it]] = make_ushort4(f2bf(f.x), f2bf(f.y), f2bf(f.z), f2bf(f.w));
      *(ushort4*)&lB[dst[it]] = *(const ushort4*)(bptr[it] + kt);
    }
    __syncthreads();
    const int ao = (w * 32 + m) * LDA + q4 * 8;
    bf16x8 a0 = *(const bf16x8*)&lA[ao];
    bf16x8 a1 = *(const bf16x8*)&lA[ao + 16 * LDA];
#pragma unroll
    for (int j = 0; j < 8; ++j) {
      bf16x8 b = *(const bf16x8*)&lB[(j * 16 + m) * LDA + q4 * 8];
      acc[0][j] = mfma16(a0, b, acc[0][j]);
      acc[1][j] = mfma16(a1, b, acc[1][j]);
    }
    __syncthreads();
  }
  const float gain = QG[h] * QSCALE;
#pragma unroll
  for (int i = 0; i < 2; ++i)
#pragma unroll
    for (int r = 0; r < 4; ++r) {
      float ss = 0.f;
#pragma unroll
      for (int j = 0; j < 8; ++j) { float vv = acc[i][j][r]; ss += vv * vv; }
      ss += __shfl_xor(ss, 1); ss += __shfl_xor(ss, 2);
      ss += __shfl_xor(ss, 4); ss += __shfl_xor(ss, 8);
      const float sc = rsqrtf(ss * (1.0f / 128.0f) + EPSI);
      const int gr = row0 + w * 32 + i * 16 + q4 * 4 + r;
      unsigned short* op = Q + (size_t)gr * DIMM + col0;
#pragma unroll
      for (int j = 0; j < 4; ++j) {
        const int c = j * 16 + m;
        const float inv = __expf((float)c * NLN64);
        float s1, c1, s2, c2;
        __sincosf(7.0f * inv, &s1, &c1);
        __sincosf(8.0f * inv, &s2, &c2);
        const float n1 = acc[i][j][r] * sc;
        const float n2 = acc[i][j + 4][r] * sc;
        op[c]      = f2bf((n1 * c1 + n2 * s1) * gain);
        op[c + 64] = f2bf((n2 * c2 - n1 * s2) * gain);
      }
    }
}

// ---------------- fused K+V GEMM over kv_source rows (n,d) ----------------
__global__ __launch_bounds__(256, 2)
void gemm_kv_kernel(const float* __restrict__ X, const float* __restrict__ DH,
                    const unsigned short* __restrict__ WK, const unsigned short* __restrict__ WV,
                    unsigned short* __restrict__ K, unsigned short* __restrict__ V) {
  __shared__ unsigned short lA[128 * LDA];
  __shared__ unsigned short lBk[128 * LDA];
  __shared__ unsigned short lBv[128 * LDA];
  const int t = threadIdx.x;
  const int lane = t & 63, w = t >> 6;
  const int m = lane & 15, q4 = lane >> 4;
  const int row0 = blockIdx.y * 128;   // (n,d) row base
  const int col0 = blockIdx.x * 128;   // kv feature base (one kv head)

  f32x4 acck[2][8], accv[2][8];
#pragma unroll
  for (int i = 0; i < 2; ++i)
#pragma unroll
    for (int j = 0; j < 8; ++j) { acck[i][j] = (f32x4){0.f,0.f,0.f,0.f}; accv[i][j] = (f32x4){0.f,0.f,0.f,0.f}; }

  const float* aptr[4]; const unsigned short* kptr[4]; const unsigned short* vptr[4]; int dst[4];
#pragma unroll
  for (int it = 0; it < 4; ++it) {
    int idx = t + it * 256;
    int r = idx >> 3, c = (idx & 7) * 4;
    int gr = row0 + r;
    int n = gr >> 3, d = gr & 7;
    aptr[it] = (d == 7) ? (X + (size_t)n * DIMM + c) : (DH + ((size_t)n * 7 + d) * DIMM + c);
    kptr[it] = WK + (size_t)(col0 + r) * DIMM + c;
    vptr[it] = WV + (size_t)(col0 + r) * DIMM + c;
    dst[it] = r * LDA + c;
  }
  for (int kt = 0; kt < DIMM; kt += 32) {
#pragma unroll
    for (int it = 0; it < 4; ++it) {
      float4 f = *(const float4*)(aptr[it] + kt);
      *(ushort4*)&lA[dst[it]]  = make_ushort4(f2bf(f.x), f2bf(f.y), f2bf(f.z), f2bf(f.w));
      *(ushort4*)&lBk[dst[it]] = *(const ushort4*)(kptr[it] + kt);
      *(ushort4*)&lBv[dst[it]] = *(const ushort4*)(vptr[it] + kt);
    }
    __syncthreads();
    const int ao = (w * 32 + m) * LDA + q4 * 8;
    bf16x8 a0 = *(const bf16x8*)&lA[ao];
    bf16x8 a1 = *(const bf16x8*)&lA[ao + 16 * LDA];
#pragma unroll
    for (int j = 0; j < 8; ++j) {
      const int bo = (j * 16 + m) * LDA + q4 * 8;
      bf16x8 bk = *(const bf16x8*)&lBk[bo];
      acck[0][j] = mfma16(a0, bk, acck[0][j]);
      acck[1][j] = mfma16(a1, bk, acck[1][j]);
      bf16x8 bv = *(const bf16x8*)&lBv[bo];
      accv[0][j] = mfma16(a0, bv, accv[0][j]);
      accv[1][j] = mfma16(a1, bv, accv[1][j]);
    }
    __syncthreads();
  }
#pragma unroll
  for (int i = 0; i < 2; ++i)
#pragma unroll
    for (int r = 0; r < 4; ++r) {
      const int gr = row0 + w * 32 + i * 16 + q4 * 4 + r;
      // ---- V: plain bf16 store ----
      unsigned short* vp = V + (size_t)gr * KVD + col0;
#pragma unroll
      for (int j = 0; j < 8; ++j) vp[j * 16 + m] = f2bf(accv[i][j][r]);
      // ---- K: rmsnorm + depth rope ----
      float ss = 0.f;
#pragma unroll
      for (int j = 0; j < 8; ++j) { float vv = acck[i][j][r]; ss += vv * vv; }
      ss += __shfl_xor(ss, 1); ss += __shfl_xor(ss, 2);
      ss += __shfl_xor(ss, 4); ss += __shfl_xor(ss, 8);
      const float sc = rsqrtf(ss * (1.0f / 128.0f) + EPSI);
      const int d = gr & 7;
      const float fd = (float)d, fr = (float)(15 - d);
      unsigned short* kp = K + (size_t)gr * KVD + col0;
#pragma unroll
      for (int j = 0; j < 4; ++j) {
        const int c = j * 16 + m;
        const float inv = __expf((float)c * NLN64);
        float s1, c1, s2, c2;
        __sincosf(fd * inv, &s1, &c1);
        __sincosf(fr * inv, &s2, &c2);
        const float n1 = acck[i][j][r] * sc;
        const float n2 = acck[i][j + 4][r] * sc;
        kp[c]      = f2bf(n1 * c1 + n2 * s1);
        kp[c + 64] = f2bf(n2 * c2 - n1 * s2);
      }
    }
}

// ---------------- attention: depth=8 softmax per (token, head) ----------------
__global__ __launch_bounds__(256)
void attn_kernel(const unsigned short* __restrict__ Q, const unsigned short* __restrict__ K,
                 const unsigned short* __restrict__ V, unsigned short* __restrict__ Y) {
  __shared__ unsigned short lK[NDEPTH * KVD];
  __shared__ unsigned short lV[NDEPTH * KVD];
  const int n = blockIdx.x;
  const int t = threadIdx.x;
#pragma unroll
  for (int i = 0; i < 4; ++i) {
    int idx = t * 4 + i * 1024;
    *(ushort4*)&lK[idx] = *(const ushort4*)&K[(size_t)n * (NDEPTH * KVD) + idx];
    *(ushort4*)&lV[idx] = *(const ushort4*)&V[(size_t)n * (NDEPTH * KVD) + idx];
  }
  __syncthreads();
  const int h = t >> 4, sub = t & 15;
  const int c0 = sub * 8;
  const int hk = h >> 2;
  const unsigned short* qp = Q + (size_t)n * DIMM + h * HDIM + c0;
  ushort4 qa = *(const ushort4*)qp;
  ushort4 qb = *(const ushort4*)(qp + 4);
  float qv[8] = {bf2f(qa.x), bf2f(qa.y), bf2f(qa.z), bf2f(qa.w),
                 bf2f(qb.x), bf2f(qb.y), bf2f(qb.z), bf2f(qb.w)};
  float s[NDEPTH];
#pragma unroll
  for (int d = 0; d < NDEPTH; ++d) {
    const unsigned short* kp = &lK[d * KVD + hk * HDIM + c0];
    ushort4 ka = *(const ushort4*)kp;
    ushort4 kb = *(const ushort4*)(kp + 4);
    float p = qv[0]*bf2f(ka.x) + qv[1]*bf2f(ka.y) + qv[2]*bf2f(ka.z) + qv[3]*bf2f(ka.w)
            + qv[4]*bf2f(kb.x) + qv[5]*bf2f(kb.y) + qv[6]*bf2f(kb.z) + qv[7]*bf2f(kb.w);
    p += __shfl_xor(p, 1); p += __shfl_xor(p, 2);
    p += __shfl_xor(p, 4); p += __shfl_xor(p, 8);
    s[d] = p;
  }
  float mx = s[0];
#pragma unroll
  for (int d = 1; d < NDEPTH; ++d) mx = fmaxf(mx, s[d]);
  float sum = 0.f;
#pragma unroll
  for (int d = 0; d < NDEPTH; ++d) { s[d] = __expf(s[d] - mx); sum += s[d]; }
  const float rs = 1.0f / sum;
  float yv[8] = {0.f,0.f,0.f,0.f,0.f,0.f,0.f,0.f};
#pragma unroll
  for (int d = 0; d < NDEPTH; ++d) {
    const float p = s[d] * rs;
    const unsigned short* vp = &lV[d * KVD + hk * HDIM + c0];
    ushort4 va = *(const ushort4*)vp;
    ushort4 vb = *(const ushort4*)(vp + 4);
    yv[0] += p*bf2f(va.x); yv[1] += p*bf2f(va.y); yv[2] += p*bf2f(va.z); yv[3] += p*bf2f(va.w);
    yv[4] += p*bf2f(vb.x); yv[5] += p*bf2f(vb.y); yv[6] += p*bf2f(vb.z); yv[7] += p*bf2f(vb.w);
  }
  unsigned short* yp = Y + (size_t)n * DIMM + h * HDIM + c0;
  *(ushort4*)yp       = make_ushort4(f2bf(yv[0]), f2bf(yv[1]), f2bf(yv[2]), f2bf(yv[3]));
  *(ushort4*)(yp + 4) = make_ushort4(f2bf(yv[4]), f2bf(yv[5]), f2bf(yv[6]), f2bf(yv[7]));
}

// ---------------- Proj GEMM: out = y @ Wproj^T (fp32 out) ----------------
__global__ __launch_bounds__(256, 2)
void gemm_proj_kernel(const unsigned short* __restrict__ Yb, const unsigned short* __restrict__ W,
                      float* __restrict__ OUT) {
  __shared__ unsigned short lA[128 * LDA];
  __shared__ unsigned short lB[128 * LDA];
  const int t = threadIdx.x;
  const int lane = t & 63, w = t >> 6;
  const int m = lane & 15, q4 = lane >> 4;
  const int row0 = blockIdx.y * 128;
  const int col0 = blockIdx.x * 128;

  f32x4 acc[2][8];
#pragma unroll
  for (int i = 0; i < 2; ++i)
#pragma unroll
    for (int j = 0; j < 8; ++j) acc[i][j] = (f32x4){0.f, 0.f, 0.f, 0.f};

  const unsigned short* aptr[4]; const unsigned short* bptr[4]; int dst[4];
#pragma unroll
  for (int it = 0; it < 4; ++it) {
    int idx = t + it * 256;
    int r = idx >> 3, c = (idx & 7) * 4;
    aptr[it] = Yb + (size_t)(row0 + r) * DIMM + c;
    bptr[it] = W + (size_t)(col0 + r) * DIMM + c;
    dst[it] = r * LDA + c;
  }
  for (int kt = 0; kt < DIMM; kt += 32) {
#pragma unroll
    for (int it = 0; it < 4; ++it) {
      *(ushort4*)&lA[dst[it]] = *(const ushort4*)(aptr[it] + kt);
      *(ushort4*)&lB[dst[it]] = *(const ushort4*)(bptr[it] + kt);
    }
    __syncthreads();
    const int ao = (w * 32 + m) * LDA + q4 * 8;
    bf16x8 a0 = *(const bf16x8*)&lA[ao];
    bf16x8 a1 = *(const bf16x8*)&lA[ao + 16 * LDA];
#pragma unroll
    for (int j = 0; j < 8; ++j) {
      bf16x8 b = *(const bf16x8*)&lB[(j * 16 + m) * LDA + q4 * 8];
      acc[0][j] = mfma16(a0, b, acc[0][j]);
      acc[1][j] = mfma16(a1, b, acc[1][j]);
    }
    __syncthreads();
  }
#pragma unroll
  for (int i = 0; i < 2; ++i)
#pragma unroll
    for (int r = 0; r < 4; ++r) {
      const int gr = row0 + w * 32 + i * 16 + q4 * 4 + r;
      float* op = OUT + (size_t)gr * DIMM + col0;
#pragma unroll
      for (int j = 0; j < 8; ++j) op[j * 16 + m] = acc[i][j][r];
    }
}

extern "C" void kernel_launch(void* const* d_in, const int* in_sizes, int n_in,
                              void* d_out, int out_size, void* d_ws, size_t ws_size,
                              hipStream_t stream) {
  const float* x  = (const float*)d_in[0];
  const float* dh = (const float*)d_in[1];
  const float* Wq = (const float*)d_in[2];
  const float* Wk = (const float*)d_in[3];
  const float* Wv = (const float*)d_in[4];
  const float* Wp = (const float*)d_in[5];
  const float* qg = (const float*)d_in[6];
  float* out = (float*)d_out;
  char* ws = (char*)d_ws;

  unsigned short* wq_b = (unsigned short*)(ws + 0);          //  8.4 MB
  unsigned short* wk_b = (unsigned short*)(ws + 8388608);    //  2.1 MB
  unsigned short* wv_b = (unsigned short*)(ws + 10485760);   //  2.1 MB
  unsigned short* wp_b = (unsigned short*)(ws + 12582912);   //  8.4 MB
  unsigned short* q_b  = (unsigned short*)(ws + 20971520);   // 33.5 MB
  unsigned short* k_b  = (unsigned short*)(ws + 54525952);   // 67 MB
  unsigned short* v_b  = (unsigned short*)(ws + 121634816);  // 67 MB
  unsigned short* y_b  = (unsigned short*)(ws + 188743680);  // 33.5 MB  (total ~212 MB)

  cvt_kernel<<<4096, 256, 0, stream>>>(Wq, wq_b, 1048576);
  cvt_kernel<<<1024, 256, 0, stream>>>(Wk, wk_b, 262144);
  cvt_kernel<<<1024, 256, 0, stream>>>(Wv, wv_b, 262144);
  cvt_kernel<<<4096, 256, 0, stream>>>(Wp, wp_b, 1048576);

  gemm_q_kernel<<<dim3(16, 64), 256, 0, stream>>>(x, wq_b, qg, q_b);
  gemm_kv_kernel<<<dim3(4, 512), 256, 0, stream>>>(x, dh, wk_b, wv_b, k_b, v_b);
  attn_kernel<<<8192, 256, 0, stream>>>(q_b, k_b, v_b, y_b);
  gemm_proj_kernel<<<dim3(16, 64), 256, 0, stream>>>(y_b, wp_b, out);
}

// Round 2
// 1324.643 us; speedup vs baseline: 1.0315x; 1.0315x over previous
//
#include <hip/hip_runtime.h>
#include <cstdint>
#include <cstddef>

#define NTOK   8192
#define DIMM   2048
#define KVD    512
#define NHEAD  16
#define HDIM   128
#define NDEPTH 8
#define EPSI   1.1920929e-07f
#define QSCALE 0.08838834764831845f      /* 1/sqrt(128) */
#define NLN64  (-0.14391156831212787f)   /* -ln(10000)/64 */

typedef __attribute__((ext_vector_type(8))) short bf16x8;
typedef __attribute__((ext_vector_type(4))) float f32x4;

__device__ __forceinline__ unsigned short f2bf(float f) {
  union { float f; unsigned int u; } v; v.f = f;
  unsigned int u = v.u;
  return (unsigned short)((u + 0x7fffu + ((u >> 16) & 1u)) >> 16);
}
__device__ __forceinline__ float bf2f(unsigned short h) {
  union { unsigned int u; float f; } v; v.u = ((unsigned int)h) << 16;
  return v.f;
}
__device__ __forceinline__ f32x4 mfma16(bf16x8 a, bf16x8 b, f32x4 c) {
  return __builtin_amdgcn_mfma_f32_16x16x32_bf16(a, b, c, 0, 0, 0);
}
// async global->LDS, 16B per lane. LDS dest must be wave-uniform base + lane*16.
__device__ __forceinline__ void gl_lds16(const unsigned short* g, unsigned short* l) {
  __builtin_amdgcn_global_load_lds((const __attribute__((address_space(1))) unsigned int*)g,
                                   (__attribute__((address_space(3))) unsigned int*)l,
                                   16, 0, 0);
}

// ---------------- weight fp32 -> bf16 ----------------
__global__ __launch_bounds__(256) void cvt_kernel(const float* __restrict__ in,
                                                  unsigned short* __restrict__ out, int n4) {
  int i = blockIdx.x * 256 + threadIdx.x;
  if (i < n4) {
    float4 f = *(const float4*)(in + (size_t)i * 4);
    *(ushort4*)(out + (size_t)i * 4) = make_ushort4(f2bf(f.x), f2bf(f.y), f2bf(f.z), f2bf(f.w));
  }
}

// ---------------- Q GEMM: 256x128 tile, 4 stacked waves (64x128 each) ----------------
__global__ __launch_bounds__(256, 2)
void gemm_q_kernel(const float* __restrict__ X, const unsigned short* __restrict__ W,
                   const float* __restrict__ QG, unsigned short* __restrict__ Q) {
  __shared__ unsigned short lA[256 * 32];
  __shared__ unsigned short lB[128 * 32];
  const int t = threadIdx.x, lane = t & 63, w = t >> 6;
  const int m = lane & 15, q4 = lane >> 4;
  const int row0 = blockIdx.y * 256, h = blockIdx.x, col0 = h * 128;

  f32x4 acc[4][8];
#pragma unroll
  for (int i = 0; i < 4; ++i)
#pragma unroll
    for (int j = 0; j < 8; ++j) acc[i][j] = (f32x4){0.f, 0.f, 0.f, 0.f};

  const int ra = t >> 1, ca = (t & 1) * 16;   // A staging: rows ra, ra+128
  const int rb = t >> 2, cb = (t & 3) * 8;    // B staging: rows rb, rb+64

  const float* asrc0 = X + (size_t)(row0 + ra) * DIMM + ca;
  const float* asrc1 = X + (size_t)(row0 + 128 + ra) * DIMM + ca;
  const unsigned short* bsrc0 = W + (size_t)(col0 + rb) * DIMM + cb;
  const unsigned short* bsrc1 = W + (size_t)(col0 + rb + 64) * DIMM + cb;

  for (int kt = 0; kt < DIMM; kt += 32) {
    gl_lds16(bsrc0 + kt, &lB[(size_t)t * 8]);
    gl_lds16(bsrc1 + kt, &lB[((size_t)t + 256) * 8]);
#pragma unroll
    for (int i = 0; i < 2; ++i) {
      const float* src = (i == 0 ? asrc0 : asrc1) + kt;
      float4 f0 = *(const float4*)(src);
      float4 f1 = *(const float4*)(src + 4);
      float4 f2 = *(const float4*)(src + 8);
      float4 f3 = *(const float4*)(src + 12);
      unsigned short* dst = &lA[(i * 128 + ra) * 32 + ca];
      ((ushort4*)dst)[0] = make_ushort4(f2bf(f0.x), f2bf(f0.y), f2bf(f0.z), f2bf(f0.w));
      ((ushort4*)dst)[1] = make_ushort4(f2bf(f1.x), f2bf(f1.y), f2bf(f1.z), f2bf(f1.w));
      ((ushort4*)dst)[2] = make_ushort4(f2bf(f2.x), f2bf(f2.y), f2bf(f2.z), f2bf(f2.w));
      ((ushort4*)dst)[3] = make_ushort4(f2bf(f3.x), f2bf(f3.y), f2bf(f3.z), f2bf(f3.w));
    }
    __syncthreads();
    bf16x8 a[4];
#pragma unroll
    for (int i = 0; i < 4; ++i) a[i] = *(const bf16x8*)&lA[(w * 64 + i * 16 + m) * 32 + q4 * 8];
#pragma unroll
    for (int j = 0; j < 8; ++j) {
      bf16x8 b = *(const bf16x8*)&lB[(j * 16 + m) * 32 + q4 * 8];
#pragma unroll
      for (int i = 0; i < 4; ++i) acc[i][j] = mfma16(a[i], b, acc[i][j]);
    }
    __syncthreads();
  }
  const float gain = QG[h] * QSCALE;
#pragma unroll
  for (int i = 0; i < 4; ++i)
#pragma unroll
    for (int r = 0; r < 4; ++r) {
      float ss = 0.f;
#pragma unroll
      for (int j = 0; j < 8; ++j) { float vv = acc[i][j][r]; ss += vv * vv; }
      ss += __shfl_xor(ss, 1); ss += __shfl_xor(ss, 2);
      ss += __shfl_xor(ss, 4); ss += __shfl_xor(ss, 8);
      const float sc = rsqrtf(ss * (1.0f / 128.0f) + EPSI);
      const int gr = row0 + w * 64 + i * 16 + q4 * 4 + r;
      unsigned short* op = Q + (size_t)gr * DIMM + col0;
#pragma unroll
      for (int j = 0; j < 4; ++j) {
        const int c = j * 16 + m;
        const float inv = __expf((float)c * NLN64);
        float s1, c1, s2, c2;
        __sincosf(7.0f * inv, &s1, &c1);
        __sincosf(8.0f * inv, &s2, &c2);
        const float n1 = acc[i][j][r] * sc;
        const float n2 = acc[i][j + 4][r] * sc;
        op[c]      = f2bf((n1 * c1 + n2 * s1) * gain);
        op[c + 64] = f2bf((n2 * c2 - n1 * s2) * gain);
      }
    }
}

// ---------------- fused K+V GEMM: 128x128 tile, 2x2 waves (64x64 each) ----------------
// col-tile swizzle T = wc*2 + j + (j&2): wave wc holds cols {wc*32..+31} U {64+wc*32..+31}
// so RoPE pairs (c, c+64) stay wave-local; RMSNorm row-sum reduced via LDS across wc.
__global__ __launch_bounds__(256, 2)
void gemm_kv_kernel(const float* __restrict__ X, const float* __restrict__ DH,
                    const unsigned short* __restrict__ WK, const unsigned short* __restrict__ WV,
                    unsigned short* __restrict__ K, unsigned short* __restrict__ V) {
  __shared__ unsigned short lA[128 * 32];
  __shared__ unsigned short lBk[128 * 32];
  __shared__ unsigned short lBv[128 * 32];
  __shared__ float red[128 * 2];
  const int t = threadIdx.x, lane = t & 63, w = t >> 6;
  const int m = lane & 15, q4 = lane >> 4;
  const int wr = w >> 1, wc = w & 1;
  const int row0 = blockIdx.y * 128, col0 = blockIdx.x * 128;

  f32x4 acck[4][4], accv[4][4];
#pragma unroll
  for (int i = 0; i < 4; ++i)
#pragma unroll
    for (int j = 0; j < 4; ++j) { acck[i][j] = (f32x4){0.f,0.f,0.f,0.f}; accv[i][j] = (f32x4){0.f,0.f,0.f,0.f}; }

  const int ra = t >> 1, ca = (t & 1) * 16;
  const int rb = t >> 2, cb = (t & 3) * 8;
  const int gra = row0 + ra, an = gra >> 3, ad = gra & 7;
  const float* asrc = ((ad == 7) ? (X + (size_t)an * DIMM) : (DH + ((size_t)an * 7 + ad) * DIMM)) + ca;
  const unsigned short* bk0 = WK + (size_t)(col0 + rb) * DIMM + cb;
  const unsigned short* bk1 = WK + (size_t)(col0 + rb + 64) * DIMM + cb;
  const unsigned short* bv0 = WV + (size_t)(col0 + rb) * DIMM + cb;
  const unsigned short* bv1 = WV + (size_t)(col0 + rb + 64) * DIMM + cb;

  for (int kt = 0; kt < DIMM; kt += 32) {
    gl_lds16(bk0 + kt, &lBk[(size_t)t * 8]);
    gl_lds16(bk1 + kt, &lBk[((size_t)t + 256) * 8]);
    gl_lds16(bv0 + kt, &lBv[(size_t)t * 8]);
    gl_lds16(bv1 + kt, &lBv[((size_t)t + 256) * 8]);
    {
      const float* src = asrc + kt;
      float4 f0 = *(const float4*)(src);
      float4 f1 = *(const float4*)(src + 4);
      float4 f2 = *(const float4*)(src + 8);
      float4 f3 = *(const float4*)(src + 12);
      unsigned short* dst = &lA[ra * 32 + ca];
      ((ushort4*)dst)[0] = make_ushort4(f2bf(f0.x), f2bf(f0.y), f2bf(f0.z), f2bf(f0.w));
      ((ushort4*)dst)[1] = make_ushort4(f2bf(f1.x), f2bf(f1.y), f2bf(f1.z), f2bf(f1.w));
      ((ushort4*)dst)[2] = make_ushort4(f2bf(f2.x), f2bf(f2.y), f2bf(f2.z), f2bf(f2.w));
      ((ushort4*)dst)[3] = make_ushort4(f2bf(f3.x), f2bf(f3.y), f2bf(f3.z), f2bf(f3.w));
    }
    __syncthreads();
    bf16x8 a[4];
#pragma unroll
    for (int i = 0; i < 4; ++i) a[i] = *(const bf16x8*)&lA[(wr * 64 + i * 16 + m) * 32 + q4 * 8];
#pragma unroll
    for (int j = 0; j < 4; ++j) {
      const int T = wc * 2 + j + (j & 2);
      bf16x8 bk = *(const bf16x8*)&lBk[(T * 16 + m) * 32 + q4 * 8];
      bf16x8 bv = *(const bf16x8*)&lBv[(T * 16 + m) * 32 + q4 * 8];
#pragma unroll
      for (int i = 0; i < 4; ++i) {
        acck[i][j] = mfma16(a[i], bk, acck[i][j]);
        accv[i][j] = mfma16(a[i], bv, accv[i][j]);
      }
    }
    __syncthreads();
  }
  // ---- V store + K partial row-sums ----
#pragma unroll
  for (int i = 0; i < 4; ++i)
#pragma unroll
    for (int r = 0; r < 4; ++r) {
      const int lr = wr * 64 + i * 16 + q4 * 4 + r;
      const int gr = row0 + lr;
      unsigned short* vp = V + (size_t)gr * KVD + col0;
#pragma unroll
      for (int j = 0; j < 4; ++j) {
        const int T = wc * 2 + j + (j & 2);
        vp[T * 16 + m] = f2bf(accv[i][j][r]);
      }
      float ss = 0.f;
#pragma unroll
      for (int j = 0; j < 4; ++j) { float vv = acck[i][j][r]; ss += vv * vv; }
      ss += __shfl_xor(ss, 1); ss += __shfl_xor(ss, 2);
      ss += __shfl_xor(ss, 4); ss += __shfl_xor(ss, 8);
      if (m == 0) red[lr * 2 + wc] = ss;
    }
  __syncthreads();
  // ---- K: rmsnorm + depth rope ----
#pragma unroll
  for (int i = 0; i < 4; ++i)
#pragma unroll
    for (int r = 0; r < 4; ++r) {
      const int lr = wr * 64 + i * 16 + q4 * 4 + r;
      const int gr = row0 + lr;
      const float sc = rsqrtf((red[lr * 2] + red[lr * 2 + 1]) * (1.0f / 128.0f) + EPSI);
      const int d = gr & 7;
      const float fd = (float)d, fr = (float)(15 - d);
      unsigned short* kp = K + (size_t)gr * KVD + col0;
#pragma unroll
      for (int j = 0; j < 2; ++j) {
        const int c = (wc * 2 + j) * 16 + m;
        const float inv = __expf((float)c * NLN64);
        float s1, c1, s2, c2;
        __sincosf(fd * inv, &s1, &c1);
        __sincosf(fr * inv, &s2, &c2);
        const float n1 = acck[i][j][r] * sc;
        const float n2 = acck[i][j + 2][r] * sc;
        kp[c]      = f2bf(n1 * c1 + n2 * s1);
        kp[c + 64] = f2bf(n2 * c2 - n1 * s2);
      }
    }
}

// ---------------- attention: depth=8 softmax per (token, head) ----------------
__global__ __launch_bounds__(256)
void attn_kernel(const unsigned short* __restrict__ Q, const unsigned short* __restrict__ K,
                 const unsigned short* __restrict__ V, unsigned short* __restrict__ Y) {
  __shared__ unsigned short lK[NDEPTH * KVD];
  __shared__ unsigned short lV[NDEPTH * KVD];
  const int n = blockIdx.x;
  const int t = threadIdx.x;
#pragma unroll
  for (int i = 0; i < 4; ++i) {
    int idx = t * 4 + i * 1024;
    *(ushort4*)&lK[idx] = *(const ushort4*)&K[(size_t)n * (NDEPTH * KVD) + idx];
    *(ushort4*)&lV[idx] = *(const ushort4*)&V[(size_t)n * (NDEPTH * KVD) + idx];
  }
  __syncthreads();
  const int h = t >> 4, sub = t & 15;
  const int c0 = sub * 8;
  const int hk = h >> 2;
  const unsigned short* qp = Q + (size_t)n * DIMM + h * HDIM + c0;
  ushort4 qa = *(const ushort4*)qp;
  ushort4 qb = *(const ushort4*)(qp + 4);
  float qv[8] = {bf2f(qa.x), bf2f(qa.y), bf2f(qa.z), bf2f(qa.w),
                 bf2f(qb.x), bf2f(qb.y), bf2f(qb.z), bf2f(qb.w)};
  float s[NDEPTH];
#pragma unroll
  for (int d = 0; d < NDEPTH; ++d) {
    const unsigned short* kp = &lK[d * KVD + hk * HDIM + c0];
    ushort4 ka = *(const ushort4*)kp;
    ushort4 kb = *(const ushort4*)(kp + 4);
    float p = qv[0]*bf2f(ka.x) + qv[1]*bf2f(ka.y) + qv[2]*bf2f(ka.z) + qv[3]*bf2f(ka.w)
            + qv[4]*bf2f(kb.x) + qv[5]*bf2f(kb.y) + qv[6]*bf2f(kb.z) + qv[7]*bf2f(kb.w);
    p += __shfl_xor(p, 1); p += __shfl_xor(p, 2);
    p += __shfl_xor(p, 4); p += __shfl_xor(p, 8);
    s[d] = p;
  }
  float mx = s[0];
#pragma unroll
  for (int d = 1; d < NDEPTH; ++d) mx = fmaxf(mx, s[d]);
  float sum = 0.f;
#pragma unroll
  for (int d = 0; d < NDEPTH; ++d) { s[d] = __expf(s[d] - mx); sum += s[d]; }
  const float rs = 1.0f / sum;
  float yv[8] = {0.f,0.f,0.f,0.f,0.f,0.f,0.f,0.f};
#pragma unroll
  for (int d = 0; d < NDEPTH; ++d) {
    const float p = s[d] * rs;
    const unsigned short* vp = &lV[d * KVD + hk * HDIM + c0];
    ushort4 va = *(const ushort4*)vp;
    ushort4 vb = *(const ushort4*)(vp + 4);
    yv[0] += p*bf2f(va.x); yv[1] += p*bf2f(va.y); yv[2] += p*bf2f(va.z); yv[3] += p*bf2f(va.w);
    yv[4] += p*bf2f(vb.x); yv[5] += p*bf2f(vb.y); yv[6] += p*bf2f(vb.z); yv[7] += p*bf2f(vb.w);
  }
  unsigned short* yp = Y + (size_t)n * DIMM + h * HDIM + c0;
  *(ushort4*)yp       = make_ushort4(f2bf(yv[0]), f2bf(yv[1]), f2bf(yv[2]), f2bf(yv[3]));
  *(ushort4*)(yp + 4) = make_ushort4(f2bf(yv[4]), f2bf(yv[5]), f2bf(yv[6]), f2bf(yv[7]));
}

// ---------------- Proj GEMM: 256x128 tile, stacked waves, full global_load_lds ----------------
__global__ __launch_bounds__(256, 2)
void gemm_proj_kernel(const unsigned short* __restrict__ Yb, const unsigned short* __restrict__ W,
                      float* __restrict__ OUT) {
  __shared__ unsigned short lA[256 * 32];
  __shared__ unsigned short lB[128 * 32];
  const int t = threadIdx.x, lane = t & 63, w = t >> 6;
  const int m = lane & 15, q4 = lane >> 4;
  const int row0 = blockIdx.y * 256, col0 = blockIdx.x * 128;

  f32x4 acc[4][8];
#pragma unroll
  for (int i = 0; i < 4; ++i)
#pragma unroll
    for (int j = 0; j < 8; ++j) acc[i][j] = (f32x4){0.f, 0.f, 0.f, 0.f};

  const int rb = t >> 2, cb = (t & 3) * 8;
  const unsigned short* as0 = Yb + (size_t)(row0 + rb) * DIMM + cb;
  const unsigned short* bs0 = W + (size_t)(col0 + rb) * DIMM + cb;

  for (int kt = 0; kt < DIMM; kt += 32) {
#pragma unroll
    for (int i = 0; i < 4; ++i)
      gl_lds16(as0 + (size_t)i * 64 * DIMM + kt, &lA[((size_t)t + i * 256) * 8]);
    gl_lds16(bs0 + kt, &lB[(size_t)t * 8]);
    gl_lds16(bs0 + (size_t)64 * DIMM + kt, &lB[((size_t)t + 256) * 8]);
    __syncthreads();
    bf16x8 a[4];
#pragma unroll
    for (int i = 0; i < 4; ++i) a[i] = *(const bf16x8*)&lA[(w * 64 + i * 16 + m) * 32 + q4 * 8];
#pragma unroll
    for (int j = 0; j < 8; ++j) {
      bf16x8 b = *(const bf16x8*)&lB[(j * 16 + m) * 32 + q4 * 8];
#pragma unroll
      for (int i = 0; i < 4; ++i) acc[i][j] = mfma16(a[i], b, acc[i][j]);
    }
    __syncthreads();
  }
#pragma unroll
  for (int i = 0; i < 4; ++i)
#pragma unroll
    for (int r = 0; r < 4; ++r) {
      const int gr = row0 + w * 64 + i * 16 + q4 * 4 + r;
      float* op = OUT + (size_t)gr * DIMM + col0;
#pragma unroll
      for (int j = 0; j < 8; ++j) op[j * 16 + m] = acc[i][j][r];
    }
}

extern "C" void kernel_launch(void* const* d_in, const int* in_sizes, int n_in,
                              void* d_out, int out_size, void* d_ws, size_t ws_size,
                              hipStream_t stream) {
  const float* x  = (const float*)d_in[0];
  const float* dh = (const float*)d_in[1];
  const float* Wq = (const float*)d_in[2];
  const float* Wk = (const float*)d_in[3];
  const float* Wv = (const float*)d_in[4];
  const float* Wp = (const float*)d_in[5];
  const float* qg = (const float*)d_in[6];
  float* out = (float*)d_out;
  char* ws = (char*)d_ws;

  unsigned short* wq_b = (unsigned short*)(ws + 0);          //  8.4 MB
  unsigned short* wk_b = (unsigned short*)(ws + 8388608);    //  2.1 MB
  unsigned short* wv_b = (unsigned short*)(ws + 10485760);   //  2.1 MB
  unsigned short* wp_b = (unsigned short*)(ws + 12582912);   //  8.4 MB
  unsigned short* q_b  = (unsigned short*)(ws + 20971520);   // 33.5 MB
  unsigned short* k_b  = (unsigned short*)(ws + 54525952);   // 67 MB
  unsigned short* v_b  = (unsigned short*)(ws + 121634816);  // 67 MB
  unsigned short* y_b  = (unsigned short*)(ws + 188743680);  // 33.5 MB  (total ~212 MB)

  cvt_kernel<<<4096, 256, 0, stream>>>(Wq, wq_b, 1048576);
  cvt_kernel<<<1024, 256, 0, stream>>>(Wk, wk_b, 262144);
  cvt_kernel<<<1024, 256, 0, stream>>>(Wv, wv_b, 262144);
  cvt_kernel<<<4096, 256, 0, stream>>>(Wp, wp_b, 1048576);

  gemm_q_kernel<<<dim3(16, 32), 256, 0, stream>>>(x, wq_b, qg, q_b);
  gemm_kv_kernel<<<dim3(4, 512), 256, 0, stream>>>(x, dh, wk_b, wv_b, k_b, v_b);
  attn_kernel<<<8192, 256, 0, stream>>>(q_b, k_b, v_b, y_b);
  gemm_proj_kernel<<<dim3(16, 32), 256, 0, stream>>>(y_b, wp_b, out);
}